// Round 1
// baseline (245.272 us; speedup 1.0000x reference)
//
#include <hip/hip_runtime.h>

#define H_ 56
#define W_ 56
#define NPIX 3136      // 56*56
#define OC 256
#define IC 256
#define CPF 32
#define NB 4
#define LDS_STRIDE 64  // floats per LDS row (keeps float4 reads 16B-aligned)
#define LDS_ROWS 58    // input rows -1..56 (zero halo)

// One block per (b, o). Stage each connected input plane into a zero-haloed
// LDS tile, accumulate 3x3 taps into per-thread 1x4 output strips.
__global__ __launch_bounds__(256, 4) void sparse_conv_kernel(
    const float* __restrict__ x, const float* __restrict__ weight,
    const int* __restrict__ connections, float* __restrict__ out)
{
    __shared__ float lds[LDS_ROWS * LDS_STRIDE];

    const int bid = blockIdx.x;
    const int b = bid & 3;        // blockIdx = o*4 + b -> each XCD sees one b
    const int o = bid >> 2;
    const int t = threadIdx.x;

    // Zero entire LDS once: halo (row -1, row 56, col -1, col 56, pads) stays 0.
    for (int i = t; i < LDS_ROWS * LDS_STRIDE; i += 256) lds[i] = 0.0f;

    // Precompute staging chunk offsets (784 float4 chunks: 56 rows x 14).
    int soff[4], doff[4];
#pragma unroll
    for (int i = 0; i < 4; ++i) {
        int j = t + 256 * i;
        if (j < 784) {
            int r = j / 14, q = j - r * 14;
            soff[i] = r * 56 + q * 4;                       // within plane
            doff[i] = (r + 1) * LDS_STRIDE + 4 + q * 4;     // interior col0 at +4
        } else {
            soff[i] = -1; doff[i] = 0;
        }
    }

    // Precompute output strips (784 strips of 1x4: h = j/14, w0 = 4*(j%14)).
    int sh[4], sw[4], sbase[4];
#pragma unroll
    for (int i = 0; i < 4; ++i) {
        int j = t + 256 * i;
        if (j < 784) {
            int h = j / 14, s = j - h * 14;
            sh[i] = h; sw[i] = 4 * s;
            // input row (h-1) lives at LDS row h; col w0 at offset 4 + w0
            sbase[i] = h * LDS_STRIDE + 4 + 4 * s;
        } else {
            sh[i] = 0; sw[i] = 0; sbase[i] = -1;
        }
    }

    alignas(16) float acc[4][4] = {};

    const int*   conn  = connections + o * CPF;
    const float* wbase = weight + o * CPF * 9;
    const float* xb    = x + (size_t)b * IC * NPIX;

    for (int c = 0; c < CPF; ++c) {
        const int ch = conn[c];                 // block-uniform
        const float* plane = xb + ch * NPIX;
        float wt[9];
#pragma unroll
        for (int k = 0; k < 9; ++k) wt[k] = wbase[c * 9 + k];

        __syncthreads();                        // prev compute done before overwrite
#pragma unroll
        for (int i = 0; i < 4; ++i) {
            if (soff[i] >= 0) {
                float4 v = *reinterpret_cast<const float4*>(plane + soff[i]);
                *reinterpret_cast<float4*>(&lds[doff[i]]) = v;
            }
        }
        __syncthreads();                        // plane staged

#pragma unroll
        for (int i = 0; i < 4; ++i) {
            if (sbase[i] >= 0) {
#pragma unroll
                for (int kh = 0; kh < 3; ++kh) {
                    const float* rowp = &lds[sbase[i] + kh * LDS_STRIDE];
                    float4 m = *reinterpret_cast<const float4*>(rowp);
                    float left = rowp[-1], right = rowp[4];
                    float w0c = wt[kh * 3 + 0];
                    float w1c = wt[kh * 3 + 1];
                    float w2c = wt[kh * 3 + 2];
                    acc[i][0] += w0c * left + w1c * m.x + w2c * m.y;
                    acc[i][1] += w0c * m.x  + w1c * m.y + w2c * m.z;
                    acc[i][2] += w0c * m.y  + w1c * m.z + w2c * m.w;
                    acc[i][3] += w0c * m.z  + w1c * m.w + w2c * right;
                }
            }
        }
    }

    float* ob = out + ((size_t)b * OC + o) * NPIX;
#pragma unroll
    for (int i = 0; i < 4; ++i) {
        if (sbase[i] >= 0) {
            *reinterpret_cast<float4*>(ob + sh[i] * 56 + sw[i]) =
                *reinterpret_cast<const float4*>(acc[i]);
        }
    }
}

extern "C" void kernel_launch(void* const* d_in, const int* in_sizes, int n_in,
                              void* d_out, int out_size, void* d_ws, size_t ws_size,
                              hipStream_t stream) {
    const float* x    = (const float*)d_in[0];
    const float* wgt  = (const float*)d_in[1];
    const int*   conn = (const int*)d_in[2];
    float* out = (float*)d_out;

    dim3 grid(NB * OC);   // 1024 blocks: blockIdx = o*4 + b
    dim3 block(256);
    hipLaunchKernelGGL(sparse_conv_kernel, grid, block, 0, stream, x, wgt, conn, out);
}

// Round 2
// 196.840 us; speedup vs baseline: 1.2461x; 1.2461x over previous
//
#include <hip/hip_runtime.h>

#define NPIX 3136      // 56*56
#define OC 256
#define IC 256
#define CPF 32
#define NB 4
#define STRIDE 68      // floats/row: (addr/16)%8 = (17*row+1+s)%8 -> row-decorrelated banks
#define ROWS 58        // input rows -1..56 (zero halo)
#define BUFSZ (ROWS * STRIDE)   // 3944 floats

// One block per (b,o). Double-buffered per-channel plane staging in LDS,
// 4x4 output tile per thread (196 active), one barrier per channel.
__global__ __launch_bounds__(256, 4) void sparse_conv_kernel(
    const float* __restrict__ x, const float* __restrict__ weight,
    const int* __restrict__ connections, float* __restrict__ out)
{
    __shared__ float lds[2 * BUFSZ];
    __shared__ float wlds[CPF * 9];
    __shared__ int   clds[CPF];

    const int bid = blockIdx.x;
    const int b = bid & 3;        // blockIdx = o*4 + b -> each XCD sees one b
    const int o = bid >> 2;
    const int t = threadIdx.x;

    // Zero both buffers once: halo cells stay 0, interior overwritten each stage.
    for (int i = t; i < 2 * BUFSZ; i += 256) lds[i] = 0.0f;
    for (int i = t; i < CPF * 9; i += 256) wlds[i] = weight[o * CPF * 9 + i];
    if (t < CPF) clds[t] = connections[o * CPF + t];

    // Staging chunk offsets: 784 float4 chunks (56 rows x 14).
    int soff[4], doff[4];
#pragma unroll
    for (int i = 0; i < 4; ++i) {
        int j = t + 256 * i;
        if (j < 784) {
            int r = j / 14, q = j - r * 14;
            soff[i] = r * 56 + q * 4;
            doff[i] = (r + 1) * STRIDE + 4 + q * 4;   // interior col0 at float idx 4
        } else {
            soff[i] = -1; doff[i] = 0;
        }
    }

    // Compute mapping: thread -> 4x4 output tile. 196 active threads.
    const bool active = (t < 196);
    const int g = t / 14;          // row group: output rows 4g..4g+3
    const int s = t - g * 14;      // col strip: output cols 4s..4s+3
    const int cbase = (4 * g) * STRIDE + 4 + 4 * s;   // lds row 4g = input row 4g-1

    const float* xb = x + (size_t)b * IC * NPIX;

    __syncthreads();   // zeros + wlds/clds visible

    // Prologue: stage channel 0 into buffer 0.
    {
        const float* plane = xb + (size_t)clds[0] * NPIX;
#pragma unroll
        for (int i = 0; i < 4; ++i) {
            if (soff[i] >= 0) {
                float4 v = *reinterpret_cast<const float4*>(plane + soff[i]);
                *reinterpret_cast<float4*>(&lds[doff[i]]) = v;
            }
        }
    }
    __syncthreads();

    float4 acc[4];
#pragma unroll
    for (int r = 0; r < 4; ++r) acc[r] = make_float4(0.f, 0.f, 0.f, 0.f);

    int cur = 0;
    for (int c = 0; c < CPF; ++c) {
        // 1) Issue next channel's global loads (latency hidden under compute).
        float4 nld[4];
        if (c + 1 < CPF) {
            const float* plane = xb + (size_t)clds[c + 1] * NPIX;
#pragma unroll
            for (int i = 0; i < 4; ++i) {
                if (soff[i] >= 0)
                    nld[i] = *reinterpret_cast<const float4*>(plane + soff[i]);
            }
        }

        // 2) Compute channel c from buf[cur].
        float wt[9];
#pragma unroll
        for (int k = 0; k < 9; ++k) wt[k] = wlds[c * 9 + k];

        if (active) {
            const float* bp = &lds[cur * BUFSZ + cbase];
            float4 m[6]; float L[6], R[6];
#pragma unroll
            for (int k = 0; k < 6; ++k) {
                const float* rp = bp + k * STRIDE;
                m[k] = *reinterpret_cast<const float4*>(rp);
                L[k] = rp[-1];
                R[k] = rp[4];
            }
#pragma unroll
            for (int r = 0; r < 4; ++r) {
#pragma unroll
                for (int kh = 0; kh < 3; ++kh) {
                    const int k = r + kh;
                    const float w0 = wt[kh * 3 + 0];
                    const float w1 = wt[kh * 3 + 1];
                    const float w2 = wt[kh * 3 + 2];
                    acc[r].x += w0 * L[k]     + w1 * m[k].x + w2 * m[k].y;
                    acc[r].y += w0 * m[k].x   + w1 * m[k].y + w2 * m[k].z;
                    acc[r].z += w0 * m[k].y   + w1 * m[k].z + w2 * m[k].w;
                    acc[r].w += w0 * m[k].z   + w1 * m[k].w + w2 * R[k];
                }
            }
        }

        // 3) Write next channel into the other buffer (waits vmcnt here only).
        if (c + 1 < CPF) {
            float* dst = &lds[(cur ^ 1) * BUFSZ];
#pragma unroll
            for (int i = 0; i < 4; ++i) {
                if (soff[i] >= 0)
                    *reinterpret_cast<float4*>(dst + doff[i]) = nld[i];
            }
        }

        // 4) One barrier per channel.
        __syncthreads();
        cur ^= 1;
    }

    if (active) {
        float* ob = out + ((size_t)b * OC + o) * NPIX + (4 * g) * 56 + 4 * s;
#pragma unroll
        for (int r = 0; r < 4; ++r)
            *reinterpret_cast<float4*>(ob + r * 56) = acc[r];
    }
}

extern "C" void kernel_launch(void* const* d_in, const int* in_sizes, int n_in,
                              void* d_out, int out_size, void* d_ws, size_t ws_size,
                              hipStream_t stream) {
    const float* x    = (const float*)d_in[0];
    const float* wgt  = (const float*)d_in[1];
    const int*   conn = (const int*)d_in[2];
    float* out = (float*)d_out;

    dim3 grid(NB * OC);   // blockIdx = o*4 + b
    dim3 block(256);
    hipLaunchKernelGGL(sparse_conv_kernel, grid, block, 0, stream, x, wgt, conn, out);
}

// Round 5
// 119.125 us; speedup vs baseline: 2.0589x; 1.6524x over previous
//
#include <hip/hip_runtime.h>
#include <stdint.h>

#define NPIX 3136      // 56*56
#define OC 256
#define IC 256
#define CPF 32
#define BUF_FLOATS 3456  // 13 DMA chunks * 256 + pad + zero row
#define ZROW 3360        // zero "row" (64 floats zeroed; serves halo rows)

typedef const __attribute__((address_space(1))) uint32_t* gptr_t;
typedef __attribute__((address_space(3))) uint32_t* lptr_t;

// lane s gets lane s-1's value within 16-lane DPP row; s%16==0 -> 0
__device__ __forceinline__ float dpp_shr1(float v) {
    return __int_as_float(__builtin_amdgcn_update_dpp(
        0, __float_as_int(v), 0x111, 0xF, 0xF, true));
}
// lane s gets lane s+1's value within 16-lane DPP row; s%16==15 -> 0
__device__ __forceinline__ float dpp_shl1(float v) {
    return __int_as_float(__builtin_amdgcn_update_dpp(
        0, __float_as_int(v), 0x101, 0xF, 0xF, true));
}

// One block per (b,o). Plane staged via global_load_lds DMA (linear layout,
// double-buffered). Thread (g = t>>4, s = t&15) computes a 4x4 output tile at
// rows 4g..4g+3, cols 4s..4s+3 (s>=14 and g>=14 are discard lanes). Column
// halos via DPP from neighbor lanes; row halos via a zeroed LDS row.
__global__ __launch_bounds__(256, 4) void sparse_conv_kernel(
    const float* __restrict__ x, const float* __restrict__ weight,
    const int* __restrict__ connections, float* __restrict__ out)
{
    __shared__ __align__(16) float buf[2][BUF_FLOATS];

    const int bid = blockIdx.x;
    const int b = bid & 3;        // each XCD sees exactly one batch's x (fits L2)
    const int o = bid >> 2;
    const int t = threadIdx.x;
    const int lane = t & 63;
    const int wv = t >> 6;

    if (t < 64) { buf[0][ZROW + t] = 0.f; buf[1][ZROW + t] = 0.f; }

    // 13 x 1KB DMA chunks: wave0 -> 0..3, wave w -> 3w+1..3w+3
    const int cbase = (wv == 0) ? 0 : (3 * wv + 1);
    const int cnum  = (wv == 0) ? 4 : 3;

    const float* xb   = x + (size_t)b * IC * NPIX;
    const int*   conn = connections + o * CPF;
    const float* wo   = weight + o * CPF * 9;

    const int s = t & 15;
    const int g = t >> 4;
    const bool active = (g < 14);

    // Prologue: stage channel 0 into buf[0].
    {
        const float* plane = xb + (size_t)conn[0] * NPIX;
        for (int i = 0; i < cnum; ++i) {
            const int chunk = cbase + i;
            int goff = chunk * 256 + lane * 4;
            if (goff > 3132) goff = 3132;          // tail clamp (writes pad region)
            __builtin_amdgcn_global_load_lds((gptr_t)(plane + goff),
                                             (lptr_t)(&buf[0][chunk * 256]),
                                             16, 0, 0);
        }
    }
    __syncthreads();   // zero row + DMA(c0) complete

    float4 acc[4];
#pragma unroll
    for (int r = 0; r < 4; ++r) acc[r] = make_float4(0.f, 0.f, 0.f, 0.f);

    int cur = 0;
    for (int c = 0; c < CPF; ++c) {
        // 1) Issue next channel's DMA into the other buffer (latency hidden).
        if (c + 1 < CPF) {
            const float* plane = xb + (size_t)conn[c + 1] * NPIX;
            float* dst = &buf[cur ^ 1][0];
            for (int i = 0; i < cnum; ++i) {
                const int chunk = cbase + i;
                int goff = chunk * 256 + lane * 4;
                if (goff > 3132) goff = 3132;
                __builtin_amdgcn_global_load_lds((gptr_t)(plane + goff),
                                                 (lptr_t)(dst + chunk * 256),
                                                 16, 0, 0);
            }
        }

        // 2) Block-uniform weights via scalar loads.
        float wt[9];
#pragma unroll
        for (int k = 0; k < 9; ++k) wt[k] = wo[c * 9 + k];

        // 3) Compute channel c from buf[cur].
        if (active) {
            const float* bp = &buf[cur][0];
#pragma unroll
            for (int k = 0; k < 6; ++k) {
                const int rr = 4 * g - 1 + k;                     // input row
                const int rc = ((unsigned)rr < 56u) ? rr * 56 : ZROW;
                const float4 m = *reinterpret_cast<const float4*>(bp + rc + 4 * s);
                const float L = dpp_shr1(m.w);                    // col 4s-1
                float       R = dpp_shl1(m.x);                    // col 4s+4
                R = (s == 13) ? 0.f : R;                          // real right edge
#pragma unroll
                for (int r = 0; r < 4; ++r) {
                    const int kh = k - r;
                    if (kh >= 0 && kh < 3) {
                        const float w0 = wt[kh * 3 + 0];
                        const float w1 = wt[kh * 3 + 1];
                        const float w2 = wt[kh * 3 + 2];
                        acc[r].x += w0 * L    + w1 * m.x + w2 * m.y;
                        acc[r].y += w0 * m.x  + w1 * m.y + w2 * m.z;
                        acc[r].z += w0 * m.y  + w1 * m.z + w2 * m.w;
                        acc[r].w += w0 * m.z  + w1 * m.w + w2 * R;
                    }
                }
            }
        }

        // 4) One barrier per channel (drains DMA vmcnt + compute).
        __syncthreads();
        cur ^= 1;
    }

    if (active && s < 14) {
        float* ob = out + ((size_t)b * OC + o) * NPIX + (4 * g) * 56 + 4 * s;
#pragma unroll
        for (int r = 0; r < 4; ++r)
            *reinterpret_cast<float4*>(ob + r * 56) = acc[r];
    }
}

extern "C" void kernel_launch(void* const* d_in, const int* in_sizes, int n_in,
                              void* d_out, int out_size, void* d_ws, size_t ws_size,
                              hipStream_t stream) {
    const float* x    = (const float*)d_in[0];
    const float* wgt  = (const float*)d_in[1];
    const int*   conn = (const int*)d_in[2];
    float* out = (float*)d_out;

    dim3 grid(4 * OC);   // blockIdx = o*4 + b
    dim3 block(256);
    hipLaunchKernelGGL(sparse_conv_kernel, grid, block, 0, stream, x, wgt, conn, out);
}